// Round 10
// baseline (528.270 us; speedup 1.0000x reference)
//
#include <hip/hip_runtime.h>

// Problem constants
#define BSZ 8
#define NH 12
#define LSEQ 1024
#define DMODEL 768
#define DHEAD 64
#define OUT_ELEMS 6291456   // 8*1024*768
#define ATTN_ELEMS 8388608  // 8*1024*1024
#define WELEM 589824        // 768*768

typedef __attribute__((ext_vector_type(8))) short short8;   // 8 x bf16 (4 VGPRs)
typedef __attribute__((ext_vector_type(4))) float f32x4;

__device__ __forceinline__ int   f2i(float x) { union { float f; int i; } c; c.f = x; return c.i; }
__device__ __forceinline__ float i2f(int x)   { union { int i; float f; } c; c.i = x; return c.f; }

__device__ __forceinline__ unsigned short f2bf(float x) {
    union { float f; unsigned u; } c; c.f = x;
    unsigned r = (c.u + 0x7FFF + ((c.u >> 16) & 1)) >> 16;   // RNE
    return (unsigned short)r;
}
__device__ __forceinline__ float bf2f(unsigned short h) {
    union { float f; unsigned u; } c; c.u = ((unsigned)h) << 16;
    return c.f;
}
__device__ __forceinline__ void split2(float x, unsigned short& h, unsigned short& l) {
    h = f2bf(x);
    l = f2bf(x - bf2f(h));
}

// ---- DPP wave-64 reductions (result valid in lane 63, broadcast via readlane) ----
template<int CTRL>
__device__ __forceinline__ float dppadd(float v) {
    return v + i2f(__builtin_amdgcn_update_dpp(0, f2i(v), CTRL, 0xF, 0xF, true));
}
template<int CTRL>
__device__ __forceinline__ float dppmax(float v) {
    return fmaxf(v, i2f(__builtin_amdgcn_update_dpp(f2i(v), f2i(v), CTRL, 0xF, 0xF, false)));
}

// 2 interleaved sum chains (masked-sum + count) -> wave totals, uniform
__device__ __forceinline__ void wsum2(float s[2]) {
#define WS(CTRL) _Pragma("unroll") for (int rr = 0; rr < 2; ++rr) { s[rr] = dppadd<CTRL>(s[rr]); }
    WS(0x111) WS(0x112) WS(0x114) WS(0x118) WS(0x142) WS(0x143)
#undef WS
#pragma unroll
    for (int rr = 0; rr < 2; ++rr) s[rr] = i2f(__builtin_amdgcn_readlane(f2i(s[rr]), 63));
}

// sum + sumsq + max interleaved chains (3-way ILP), single row
__device__ __forceinline__ void wred3(float& s, float& q, float& m) {
#define WS(CTRL) { s = dppadd<CTRL>(s); q = dppadd<CTRL>(q); m = dppmax<CTRL>(m); }
    WS(0x111) WS(0x112) WS(0x114) WS(0x118) WS(0x142) WS(0x143)
#undef WS
    s = i2f(__builtin_amdgcn_readlane(f2i(s), 63));
    q = i2f(__builtin_amdgcn_readlane(f2i(q), 63));
    m = i2f(__builtin_amdgcn_readlane(f2i(m), 63));
}

// ---------------------------------------------------------------------------
// convert: one-shot input quantization (R13). q,k -> hi bf16 planes (2-pass
// GEMM only consumes A-hi); Wq,Wk -> hi+lo planes. Scratch placement (no ws
// growth): Q-hi in the `out` region, K-hi + W planes in the `attn` region --
// both regions are dead until attn_kernel / out_mfma later overwrite them
// (same-stream dispatch order makes this race-free).
// ---------------------------------------------------------------------------
__global__ __launch_bounds__(256) void convert_kernel(
    const float* __restrict__ q, const float* __restrict__ k,
    const float* __restrict__ Wq, const float* __restrict__ Wk,
    unsigned short* __restrict__ Qh, unsigned short* __restrict__ Kh,
    unsigned short* __restrict__ Wqh, unsigned short* __restrict__ Wql,
    unsigned short* __restrict__ Wkh, unsigned short* __restrict__ Wkl) {
    const int tid = blockIdx.x * 256 + threadIdx.x;
    const int stride = gridDim.x * 256;
    for (int i = tid; i < OUT_ELEMS / 4; i += stride) {
        float4 a = ((const float4*)q)[i];
        ushort4 h;
        h.x = f2bf(a.x); h.y = f2bf(a.y); h.z = f2bf(a.z); h.w = f2bf(a.w);
        ((ushort4*)Qh)[i] = h;
        float4 b = ((const float4*)k)[i];
        h.x = f2bf(b.x); h.y = f2bf(b.y); h.z = f2bf(b.z); h.w = f2bf(b.w);
        ((ushort4*)Kh)[i] = h;
    }
    for (int i = tid; i < WELEM / 4; i += stride) {
        float4 a = ((const float4*)Wq)[i];
        ushort4 h, l;
        split2(a.x, h.x, l.x); split2(a.y, h.y, l.y);
        split2(a.z, h.z, l.z); split2(a.w, h.w, l.w);
        ((ushort4*)Wqh)[i] = h; ((ushort4*)Wql)[i] = l;
        float4 b = ((const float4*)Wk)[i];
        split2(b.x, h.x, l.x); split2(b.y, h.y, l.y);
        split2(b.z, h.z, l.z); split2(b.w, h.w, l.w);
        ((ushort4*)Wkh)[i] = h; ((ushort4*)Wkl)[i] = l;
    }
}

// ---------------------------------------------------------------------------
// proj_direct: C = A @ W^T + bias, 2-pass split-bf16, LDS-FREE (R13).
// Fragments load directly from pre-converted bf16 planes: lane (mrow,quad)
// reads contiguous short8 at [row][k0+quad*8] -- the attn-QK pattern. This
// deletes all staging split2 VALU (~200 ops/thread/k-step, the R8 proj
// bottleneck), the LDS roundtrip, and both barriers per k-step. Numerics
// bit-identical to R8's proj (same bf16 values, same MFMA order).
// Epilogue unchanged: writes hi+lo planes of C to ws for attn's 3-pass QK.
// ---------------------------------------------------------------------------
__global__ __launch_bounds__(256) void proj_direct(
    const unsigned short* __restrict__ Qh, const unsigned short* __restrict__ Kh,
    const unsigned short* __restrict__ Wqh, const unsigned short* __restrict__ Wql,
    const unsigned short* __restrict__ Wkh, const unsigned short* __restrict__ Wkl,
    const float* __restrict__ bq, const float* __restrict__ bk,
    unsigned short* __restrict__ ws) {
    const unsigned short* A; const unsigned short* Bhp; const unsigned short* Blp;
    const float* bias;
    unsigned short* hi; unsigned short* lo;
    if (blockIdx.z == 0) { A = Qh; Bhp = Wqh; Blp = Wql; bias = bq; hi = ws;                lo = ws + OUT_ELEMS; }
    else                 { A = Kh; Bhp = Wkh; Blp = Wkl; bias = bk; hi = ws + 2*OUT_ELEMS; lo = ws + 3*OUT_ELEMS; }

    const int t    = threadIdx.x;
    const int lane = t & 63;
    const int w    = t >> 6;
    const int wr   = w >> 1, wc = w & 1;
    const int mrow = lane & 15, quad = lane >> 4;
    const int m0   = blockIdx.y * 128;
    const int n0   = blockIdx.x * 128;

    const unsigned short* arow[4];
    const unsigned short* bhrow[4];
    const unsigned short* blrow[4];
#pragma unroll
    for (int i = 0; i < 4; ++i)
        arow[i] = A + (size_t)(m0 + wr * 64 + i * 16 + mrow) * DMODEL + quad * 8;
#pragma unroll
    for (int j = 0; j < 4; ++j) {
        const size_t r = (size_t)(n0 + wc * 64 + j * 16 + mrow) * DMODEL + quad * 8;
        bhrow[j] = Bhp + r;
        blrow[j] = Blp + r;
    }

    f32x4 acc[4][4];
#pragma unroll
    for (int i = 0; i < 4; ++i)
#pragma unroll
        for (int j = 0; j < 4; ++j) acc[i][j] = (f32x4){0.f, 0.f, 0.f, 0.f};

#pragma unroll 1
    for (int k0 = 0; k0 < DMODEL; k0 += 32) {
        short8 ah[4], bh8[4], bl8[4];
#pragma unroll
        for (int i = 0; i < 4; ++i) ah[i] = *(const short8*)(arow[i] + k0);
#pragma unroll
        for (int j = 0; j < 4; ++j) {
            bh8[j] = *(const short8*)(bhrow[j] + k0);
            bl8[j] = *(const short8*)(blrow[j] + k0);
        }
#pragma unroll
        for (int i = 0; i < 4; ++i)
#pragma unroll
            for (int j = 0; j < 4; ++j) {
                acc[i][j] = __builtin_amdgcn_mfma_f32_16x16x32_bf16(ah[i], bl8[j], acc[i][j], 0, 0, 0);
                acc[i][j] = __builtin_amdgcn_mfma_f32_16x16x32_bf16(ah[i], bh8[j], acc[i][j], 0, 0, 0);
            }
    }

#pragma unroll
    for (int j = 0; j < 4; ++j) {
        const int ng = n0 + wc * 64 + j * 16 + mrow;
        const float bj = bias[ng];
        const int hh = ng >> 6, dd = ng & 63;
#pragma unroll
        for (int i = 0; i < 4; ++i) {
#pragma unroll
            for (int reg = 0; reg < 4; ++reg) {
                const int mg = m0 + wr * 64 + i * 16 + quad * 4 + reg;
                const float c = acc[i][j][reg] + bj;
                unsigned short ch, cl;
                split2(c, ch, cl);
                const size_t idx = (((size_t)(mg >> 10) * NH + hh) * LSEQ + (mg & 1023)) * DHEAD + dd;
                hi[idx] = ch;
                lo[idx] = cl;
            }
        }
    }
}

// ---------------------------------------------------------------------------
// Fused scores + sparsemax + head-mean. R13 = R6 kernel byte-identical,
// __launch_bounds__(1024, 8) restored: R8 measured (1024,6) -> occupancy
// 82->47%, dur 258->283. The VGPR=32 spills are cheaper than the lost
// occupancy -- keep the empirically faster config.
// ---------------------------------------------------------------------------
__global__ __launch_bounds__(1024, 8) void attn_kernel(
    const unsigned short* __restrict__ ws, float* __restrict__ attn_out) {
    __shared__ float S[16 * 1024];    // 64 KB score tile (swizzled columns)

    const unsigned short* Qhi = ws;
    const unsigned short* Qlo = ws + OUT_ELEMS;
    const unsigned short* Khi = ws + 2 * OUT_ELEMS;
    const unsigned short* Klo = ws + 3 * OUT_ELEMS;

    const int t = threadIdx.x;
    const int lane = t & 63;
    const int w = t >> 6;             // 0..15
    const int idlin = blockIdx.x;
    const int b  = idlin & 7;         // batch -> XCD pinning (dispatch round-robins id%8)
    const int q0 = (idlin >> 3) * 16;

    const int mrow = lane & 15;
    const int quad = lane >> 4;

    float macc[16];                   // head-mean accumulator, row layout (1 row)
#pragma unroll
    for (int j = 0; j < 16; ++j) macc[j] = 0.f;

#pragma unroll 1
    for (int h = 0; h < NH; ++h) {
        const size_t hb = ((size_t)b * NH + h) * (LSEQ * DHEAD);

        // ---- QK phase: wave w covers cols [w*64, w*64+64) = 4 KV tiles ----
        {
            const size_t aoff = hb + (size_t)(q0 + mrow) * DHEAD + quad * 8;
            short8 qh0 = *(const short8*)(Qhi + aoff);
            short8 qh1 = *(const short8*)(Qhi + aoff + 32);
            short8 ql0 = *(const short8*)(Qlo + aoff);
            short8 ql1 = *(const short8*)(Qlo + aoff + 32);
#pragma unroll
            for (int nt = 0; nt < 4; ++nt) {
                const int n0 = w * 64 + nt * 16;
                const size_t boff = hb + (size_t)(n0 + mrow) * DHEAD + quad * 8;
                short8 kh0 = *(const short8*)(Khi + boff);
                short8 kh1 = *(const short8*)(Khi + boff + 32);
                short8 kl0 = *(const short8*)(Klo + boff);
                short8 kl1 = *(const short8*)(Klo + boff + 32);
                f32x4 d = (f32x4){0.f, 0.f, 0.f, 0.f};
                d = __builtin_amdgcn_mfma_f32_16x16x32_bf16(ql0, kh0, d, 0, 0, 0);
                d = __builtin_amdgcn_mfma_f32_16x16x32_bf16(qh0, kl0, d, 0, 0, 0);
                d = __builtin_amdgcn_mfma_f32_16x16x32_bf16(qh0, kh0, d, 0, 0, 0);
                d = __builtin_amdgcn_mfma_f32_16x16x32_bf16(ql1, kh1, d, 0, 0, 0);
                d = __builtin_amdgcn_mfma_f32_16x16x32_bf16(qh1, kl1, d, 0, 0, 0);
                d = __builtin_amdgcn_mfma_f32_16x16x32_bf16(qh1, kh1, d, 0, 0, 0);
                const int swcol = (n0 + mrow) ^ (quad << 4);   // 2-way banks (free)
#pragma unroll
                for (int reg = 0; reg < 4; ++reg)
                    S[(quad * 4 + reg) * 1024 + swcol] = d[reg] * 0.125f;
            }
        }
        __syncthreads();   // (a) S writes for head h complete

        // ---- z-load: wave w owns row w ----
        float z[16];
        {
            const int swz = ((w >> 2) & 3) << 4;   // inverse of write swizzle for row w
#pragma unroll
            for (int c = 0; c < 4; ++c)
                *(f32x4*)&z[c * 4] = *(const f32x4*)&S[w * 1024 + ((c * 256 + lane * 4) ^ swz)];
        }
        __syncthreads();   // (b) all waves consumed S; safe for next head's writes

        // ---- init: row sum, sumsq, max (4-way element chains) ----
        float sv, qv, mv;
        {
            float s0 = 0.f, s1 = 0.f, s2 = 0.f, s3 = 0.f;
            float p0 = 0.f, p1 = 0.f, p2 = 0.f, p3 = 0.f;
            float m0 = z[0], m1 = z[1], m2 = z[2], m3 = z[3];
#pragma unroll
            for (int j = 0; j < 16; j += 4) {
                s0 += z[j]; s1 += z[j + 1]; s2 += z[j + 2]; s3 += z[j + 3];
                p0 = fmaf(z[j],     z[j],     p0);
                p1 = fmaf(z[j + 1], z[j + 1], p1);
                p2 = fmaf(z[j + 2], z[j + 2], p2);
                p3 = fmaf(z[j + 3], z[j + 3], p3);
            }
#pragma unroll
            for (int j = 4; j < 16; j += 4) {
                m0 = fmaxf(m0, z[j]);     m1 = fmaxf(m1, z[j + 1]);
                m2 = fmaxf(m2, z[j + 2]); m3 = fmaxf(m3, z[j + 3]);
            }
            sv = (s0 + s1) + (s2 + s3);
            qv = (p0 + p1) + (p2 + p3);
            mv = fmaxf(fmaxf(m0, m1), fmaxf(m2, m3));
        }
        wred3(sv, qv, mv);

        // ---- warm start: Gaussian-tail analytic tau0 (validated in pass 1) ----
        const float t0s = fmaxf((sv - 1.0f) * (1.0f / 1024.0f), mv - 1.0f);
        float tau;
        {
            const float mu  = sv * (1.0f / 1024.0f);
            const float var = fmaxf(qv * (1.0f / 1024.0f) - mu * mu, 1e-12f);
            const float sg  = sqrtf(var);
            const float a   = 2.7196f + 0.33333f * __logf(sg);   // solves phi(a)-aQ(a)=1/(1024 sg)
            const float tg  = mu + (a - 0.25f) * sg;
            tau = fminf(fmaxf(tg, t0s), mv - 1e-3f);
        }

        // ballot-free masked pass: sum + count in float through one butterfly
#define SP_PASS(SC) do { \
        float a0 = 0.f, a1 = 0.f, a2 = 0.f, a3 = 0.f; \
        float n0 = 0.f, n1 = 0.f, n2 = 0.f, n3 = 0.f; \
        _Pragma("unroll") for (int j = 0; j < 16; j += 4) { \
            bool g0 = z[j]     > tau; \
            bool g1 = z[j + 1] > tau; \
            bool g2 = z[j + 2] > tau; \
            bool g3 = z[j + 3] > tau; \
            a0 += g0 ? z[j]     : 0.f;  n0 += g0 ? 1.f : 0.f; \
            a1 += g1 ? z[j + 1] : 0.f;  n1 += g1 ? 1.f : 0.f; \
            a2 += g2 ? z[j + 2] : 0.f;  n2 += g2 ? 1.f : 0.f; \
            a3 += g3 ? z[j + 3] : 0.f;  n3 += g3 ? 1.f : 0.f; \
        } \
        SC[0] = (a0 + a1) + (a2 + a3); \
        SC[1] = (n0 + n1) + (n2 + n3); \
        wsum2(SC); \
} while (0)

        float prev;
        // ---- pass 1: Michelot step with validity check ----
        {
            float sc[2];
            SP_PASS(sc);
            const float tn = (sc[0] - 1.0f) / sc[1];
            if (tn >= tau) { tau = tn; prev = sc[1]; }   // f(tau0)>=0: warm start valid
            else           { tau = t0s; prev = -1.f; }   // invalid/NaN: safe restart
        }
        // ---- Michelot loop (exact; per-wave uniform exit) ----
        for (int it = 0; it < 63; ++it) {
            float sc[2];
            SP_PASS(sc);
            if (sc[1] == prev) break;                    // support stable -> tau exact
            tau = (sc[0] - 1.0f) / sc[1];
            prev = sc[1];
        }
#undef SP_PASS

        // accumulate head-mean in registers (no LDS writeback)
#pragma unroll
        for (int j = 0; j < 16; ++j)
            macc[j] += fmaxf(z[j] - tau, 0.f);
    }

    float* ao = attn_out + ((size_t)b * LSEQ + q0) * LSEQ;
#pragma unroll
    for (int c = 0; c < 4; ++c) {
        f32x4 o;
#pragma unroll
        for (int j = 0; j < 4; ++j) o[j] = macc[c * 4 + j] * (1.0f / 12.0f);
        *(f32x4*)&ao[(size_t)w * LSEQ + c * 256 + lane * 4] = o;
    }
}

// ---------------------------------------------------------------------------
// out_mfma: out[b] = attn[b] @ v[b]. UNCHANGED from R8 (2-pass split-bf16).
// ---------------------------------------------------------------------------
__global__ __launch_bounds__(256) void out_mfma(
    const float* __restrict__ attn, const float* __restrict__ v,
    float* __restrict__ out) {
    const int b = blockIdx.z;
    const float* Ab = attn + (size_t)b * LSEQ * LSEQ;
    const float* Vb = v    + (size_t)b * LSEQ * DMODEL;
    float* Cb       = out  + (size_t)b * LSEQ * DMODEL;

    __shared__ unsigned short Ah[128][32], Al[128][32];
    __shared__ unsigned short Bh[128][36], Bl[128][36];   // pad 36: conflict-free 8B rd/wr

    const int t    = threadIdx.x;
    const int lane = t & 63;
    const int w    = t >> 6;
    const int wr   = w >> 1, wc = w & 1;
    const int mrow = lane & 15, quad = lane >> 4;
    const int m0   = blockIdx.y * 128;
    const int n0   = blockIdx.x * 128;

    const int srow = t >> 3;
    const int scol = (t & 7) * 4;
    const int bn   = t & 127;
    const int bk0  = (t >> 7) * 16;

    f32x4 acc[4][4];
#pragma unroll
    for (int i = 0; i < 4; ++i)
#pragma unroll
        for (int j = 0; j < 4; ++j) acc[i][j] = (f32x4){0.f, 0.f, 0.f, 0.f};

    for (int k0 = 0; k0 < LSEQ; k0 += 32) {
        float4 av[4];
#pragma unroll
        for (int i = 0; i < 4; ++i)
            av[i] = *(const float4*)&Ab[(size_t)(m0 + srow + i * 32) * LSEQ + k0 + scol];
        float bv[16];
#pragma unroll
        for (int i = 0; i < 16; ++i)
            bv[i] = Vb[(size_t)(k0 + bk0 + i) * DMODEL + n0 + bn];

        __syncthreads();
#pragma unroll
        for (int i = 0; i < 4; ++i) {
            ushort4 h4, l4;
            split2(av[i].x, h4.x, l4.x); split2(av[i].y, h4.y, l4.y);
            split2(av[i].z, h4.z, l4.z); split2(av[i].w, h4.w, l4.w);
            *(ushort4*)&Ah[srow + i * 32][scol] = h4;
            *(ushort4*)&Al[srow + i * 32][scol] = l4;
        }
#pragma unroll
        for (int g = 0; g < 4; ++g) {
            ushort4 h4, l4;
            split2(bv[g * 4 + 0], h4.x, l4.x); split2(bv[g * 4 + 1], h4.y, l4.y);
            split2(bv[g * 4 + 2], h4.z, l4.z); split2(bv[g * 4 + 3], h4.w, l4.w);
            *(ushort4*)&Bh[bn][bk0 + g * 4] = h4;
            *(ushort4*)&Bl[bn][bk0 + g * 4] = l4;
        }
        __syncthreads();

        short8 ah[4], bh[4], bl[4];
#pragma unroll
        for (int i = 0; i < 4; ++i)
            ah[i] = *(const short8*)&Ah[wr * 64 + i * 16 + mrow][quad * 8];
#pragma unroll
        for (int j = 0; j < 4; ++j) {
            const unsigned short* ph = &Bh[wc * 64 + j * 16 + mrow][quad * 8];
            const unsigned short* pl = &Bl[wc * 64 + j * 16 + mrow][quad * 8];
            uint2 h0 = *(const uint2*)ph;
            uint2 h1 = *(const uint2*)(ph + 4);
            uint2 l0 = *(const uint2*)pl;
            uint2 l1 = *(const uint2*)(pl + 4);
            union { uint u[4]; short8 s; } ch, cl;
            ch.u[0] = h0.x; ch.u[1] = h0.y; ch.u[2] = h1.x; ch.u[3] = h1.y;
            cl.u[0] = l0.x; cl.u[1] = l0.y; cl.u[2] = l1.x; cl.u[3] = l1.y;
            bh[j] = ch.s; bl[j] = cl.s;
        }
#pragma unroll
        for (int i = 0; i < 4; ++i)
#pragma unroll
            for (int j = 0; j < 4; ++j) {
                acc[i][j] = __builtin_amdgcn_mfma_f32_16x16x32_bf16(ah[i], bl[j], acc[i][j], 0, 0, 0);
                acc[i][j] = __builtin_amdgcn_mfma_f32_16x16x32_bf16(ah[i], bh[j], acc[i][j], 0, 0, 0);
            }
    }

#pragma unroll
    for (int i = 0; i < 4; ++i)
#pragma unroll
        for (int j = 0; j < 4; ++j)
#pragma unroll
            for (int reg = 0; reg < 4; ++reg) {
                const int mg = m0 + wr * 64 + i * 16 + quad * 4 + reg;
                const int ng = n0 + wc * 64 + j * 16 + mrow;
                Cb[(size_t)mg * DMODEL + ng] = acc[i][j][reg];
            }
}

extern "C" void kernel_launch(void* const* d_in, const int* in_sizes, int n_in,
                              void* d_out, int out_size, void* d_ws, size_t ws_size,
                              hipStream_t stream) {
    const float* q  = (const float*)d_in[0];
    const float* k  = (const float*)d_in[1];
    const float* v  = (const float*)d_in[2];
    const float* Wq = (const float*)d_in[3];
    const float* bq = (const float*)d_in[4];
    const float* Wk = (const float*)d_in[5];
    const float* bk = (const float*)d_in[6];

    float* out  = (float*)d_out;                 // [8,1024,768]
    float* attn = out + OUT_ELEMS;               // [8,1024,1024]
    unsigned short* ws = (unsigned short*)d_ws;  // Qhi|Qlo|Khi|Klo bf16 planes (50 MB)

    // scratch placement in not-yet-written output regions (stream-ordered):
    unsigned short* Qh  = (unsigned short*)out;        // 12.6 MB in out region (25.2 MB)
    unsigned short* Kh  = (unsigned short*)attn;       // in attn region (33.5 MB)
    unsigned short* Wqh = Kh + OUT_ELEMS;
    unsigned short* Wql = Wqh + WELEM;
    unsigned short* Wkh = Wql + WELEM;
    unsigned short* Wkl = Wkh + WELEM;

    hipLaunchKernelGGL(convert_kernel, dim3(1024), dim3(256), 0, stream,
                       q, k, Wq, Wk, Qh, Kh, Wqh, Wql, Wkh, Wkl);
    hipLaunchKernelGGL(proj_direct, dim3(6, 64, 2), dim3(256), 0, stream,
                       Qh, Kh, Wqh, Wql, Wkh, Wkl, bq, bk, ws);
    hipLaunchKernelGGL(attn_kernel, dim3(512), dim3(1024), 0, stream,
                       ws, attn);
    hipLaunchKernelGGL(out_mfma, dim3(6, 8, 8), dim3(256), 0, stream,
                       attn, v, out);
}

// Round 11
// 485.513 us; speedup vs baseline: 1.0881x; 1.0881x over previous
//
#include <hip/hip_runtime.h>

// Problem constants
#define BSZ 8
#define NH 12
#define LSEQ 1024
#define DMODEL 768
#define DHEAD 64
#define OUT_ELEMS 6291456   // 8*1024*768
#define ATTN_ELEMS 8388608  // 8*1024*1024

typedef __attribute__((ext_vector_type(8))) short short8;   // 8 x bf16 (4 VGPRs)
typedef __attribute__((ext_vector_type(4))) float f32x4;

__device__ __forceinline__ int   f2i(float x) { union { float f; int i; } c; c.f = x; return c.i; }
__device__ __forceinline__ float i2f(int x)   { union { int i; float f; } c; c.i = x; return c.f; }

__device__ __forceinline__ unsigned short f2bf(float x) {
    union { float f; unsigned u; } c; c.f = x;
    unsigned r = (c.u + 0x7FFF + ((c.u >> 16) & 1)) >> 16;   // RNE
    return (unsigned short)r;
}
__device__ __forceinline__ float bf2f(unsigned short h) {
    union { float f; unsigned u; } c; c.u = ((unsigned)h) << 16;
    return c.f;
}
__device__ __forceinline__ void split2(float x, unsigned short& h, unsigned short& l) {
    h = f2bf(x);
    l = f2bf(x - bf2f(h));
}

// ---- DPP wave-64 reductions (result valid in lane 63, broadcast via readlane) ----
template<int CTRL>
__device__ __forceinline__ float dppadd(float v) {
    return v + i2f(__builtin_amdgcn_update_dpp(0, f2i(v), CTRL, 0xF, 0xF, true));
}
template<int CTRL>
__device__ __forceinline__ float dppmax(float v) {
    return fmaxf(v, i2f(__builtin_amdgcn_update_dpp(f2i(v), f2i(v), CTRL, 0xF, 0xF, false)));
}

// 2 interleaved sum chains (masked-sum + count) -> wave totals, uniform
__device__ __forceinline__ void wsum2(float s[2]) {
#define WS(CTRL) _Pragma("unroll") for (int rr = 0; rr < 2; ++rr) { s[rr] = dppadd<CTRL>(s[rr]); }
    WS(0x111) WS(0x112) WS(0x114) WS(0x118) WS(0x142) WS(0x143)
#undef WS
#pragma unroll
    for (int rr = 0; rr < 2; ++rr) s[rr] = i2f(__builtin_amdgcn_readlane(f2i(s[rr]), 63));
}

// sum + sumsq + max interleaved chains (3-way ILP), single row
__device__ __forceinline__ void wred3(float& s, float& q, float& m) {
#define WS(CTRL) { s = dppadd<CTRL>(s); q = dppadd<CTRL>(q); m = dppmax<CTRL>(m); }
    WS(0x111) WS(0x112) WS(0x114) WS(0x118) WS(0x142) WS(0x143)
#undef WS
    s = i2f(__builtin_amdgcn_readlane(f2i(s), 63));
    q = i2f(__builtin_amdgcn_readlane(f2i(q), 63));
    m = i2f(__builtin_amdgcn_readlane(f2i(m), 63));
}

// ---------------------------------------------------------------------------
// proj_mfma: C = A @ W^T + bias, 2-pass split-bf16, LDS-staged (R8-measured
// best). R15: A-lo staging removed (2-pass consumes only ah,bh,bl -- the Al
// split2/LDS writes were dead code; output bit-identical, LDS 32->24 KB).
// R10 measured the LDS-free direct-load variant 56 us SLOWER (uncoalesced
// 16x64B wave loads + lost 4-way B sharing): LDS staging stays.
// ---------------------------------------------------------------------------
__global__ __launch_bounds__(256) void proj_mfma(
    const float* __restrict__ qin, const float* __restrict__ kin,
    const float* __restrict__ Wq, const float* __restrict__ bq,
    const float* __restrict__ Wk, const float* __restrict__ bk,
    unsigned short* __restrict__ ws) {
    const float* A; const float* W; const float* bias;
    unsigned short* hi; unsigned short* lo;
    if (blockIdx.z == 0) { A = qin; W = Wq; bias = bq; hi = ws;                lo = ws + OUT_ELEMS; }
    else                 { A = kin; W = Wk; bias = bk; hi = ws + 2*OUT_ELEMS; lo = ws + 3*OUT_ELEMS; }

    __shared__ unsigned short Ah[128][32];
    __shared__ unsigned short Bh[128][32], Bl[128][32];

    const int t    = threadIdx.x;
    const int lane = t & 63;
    const int w    = t >> 6;
    const int wr   = w >> 1, wc = w & 1;
    const int mrow = lane & 15, quad = lane >> 4;
    const int m0   = blockIdx.y * 128;
    const int n0   = blockIdx.x * 128;

    const int srow = t >> 3;
    const int scol = (t & 7) * 4;

    f32x4 acc[4][4];
#pragma unroll
    for (int i = 0; i < 4; ++i)
#pragma unroll
        for (int j = 0; j < 4; ++j) acc[i][j] = (f32x4){0.f, 0.f, 0.f, 0.f};

    for (int k0 = 0; k0 < DMODEL; k0 += 32) {
        float4 av[4], wv[4];
#pragma unroll
        for (int i = 0; i < 4; ++i) {
            av[i] = *(const float4*)&A[(size_t)(m0 + srow + i * 32) * DMODEL + k0 + scol];
            wv[i] = *(const float4*)&W[(size_t)(n0 + srow + i * 32) * DMODEL + k0 + scol];
        }
        __syncthreads();
#pragma unroll
        for (int i = 0; i < 4; ++i) {
            ushort4 h4, l4;
            h4.x = f2bf(av[i].x); h4.y = f2bf(av[i].y);
            h4.z = f2bf(av[i].z); h4.w = f2bf(av[i].w);
            *(ushort4*)&Ah[srow + i * 32][scol] = h4;
            split2(wv[i].x, h4.x, l4.x); split2(wv[i].y, h4.y, l4.y);
            split2(wv[i].z, h4.z, l4.z); split2(wv[i].w, h4.w, l4.w);
            *(ushort4*)&Bh[srow + i * 32][scol] = h4;
            *(ushort4*)&Bl[srow + i * 32][scol] = l4;
        }
        __syncthreads();

        short8 ah[4], bh[4], bl[4];
#pragma unroll
        for (int i = 0; i < 4; ++i) {
            ah[i] = *(const short8*)&Ah[wr * 64 + i * 16 + mrow][quad * 8];
            bh[i] = *(const short8*)&Bh[wc * 64 + i * 16 + mrow][quad * 8];
            bl[i] = *(const short8*)&Bl[wc * 64 + i * 16 + mrow][quad * 8];
        }
#pragma unroll
        for (int i = 0; i < 4; ++i)
#pragma unroll
            for (int j = 0; j < 4; ++j) {
                acc[i][j] = __builtin_amdgcn_mfma_f32_16x16x32_bf16(ah[i], bl[j], acc[i][j], 0, 0, 0);
                acc[i][j] = __builtin_amdgcn_mfma_f32_16x16x32_bf16(ah[i], bh[j], acc[i][j], 0, 0, 0);
            }
    }

#pragma unroll
    for (int j = 0; j < 4; ++j) {
        const int ng = n0 + wc * 64 + j * 16 + mrow;
        const float bj = bias[ng];
        const int hh = ng >> 6, dd = ng & 63;
#pragma unroll
        for (int i = 0; i < 4; ++i) {
#pragma unroll
            for (int reg = 0; reg < 4; ++reg) {
                const int mg = m0 + wr * 64 + i * 16 + quad * 4 + reg;
                const float c = acc[i][j][reg] + bj;
                unsigned short ch, cl;
                split2(c, ch, cl);
                const size_t idx = (((size_t)(mg >> 10) * NH + hh) * LSEQ + (mg & 1023)) * DHEAD + dd;
                hi[idx] = ch;
                lo[idx] = cl;
            }
        }
    }
}

// ---------------------------------------------------------------------------
// Fused scores + sparsemax + head-mean. R15 = R10's attn verbatim:
// (1024, 8) measured 258 us / 82% occupancy (vs 283 us / 47% at (1024,6)).
// VGPR=32 spills are cheaper than lost occupancy -- keep.
// ---------------------------------------------------------------------------
__global__ __launch_bounds__(1024, 8) void attn_kernel(
    const unsigned short* __restrict__ ws, float* __restrict__ attn_out) {
    __shared__ float S[16 * 1024];    // 64 KB score tile (swizzled columns)

    const unsigned short* Qhi = ws;
    const unsigned short* Qlo = ws + OUT_ELEMS;
    const unsigned short* Khi = ws + 2 * OUT_ELEMS;
    const unsigned short* Klo = ws + 3 * OUT_ELEMS;

    const int t = threadIdx.x;
    const int lane = t & 63;
    const int w = t >> 6;             // 0..15
    const int idlin = blockIdx.x;
    const int b  = idlin & 7;         // batch -> XCD pinning (dispatch round-robins id%8)
    const int q0 = (idlin >> 3) * 16;

    const int mrow = lane & 15;
    const int quad = lane >> 4;

    float macc[16];                   // head-mean accumulator, row layout (1 row)
#pragma unroll
    for (int j = 0; j < 16; ++j) macc[j] = 0.f;

#pragma unroll 1
    for (int h = 0; h < NH; ++h) {
        const size_t hb = ((size_t)b * NH + h) * (LSEQ * DHEAD);

        // ---- QK phase: wave w covers cols [w*64, w*64+64) = 4 KV tiles ----
        {
            const size_t aoff = hb + (size_t)(q0 + mrow) * DHEAD + quad * 8;
            short8 qh0 = *(const short8*)(Qhi + aoff);
            short8 qh1 = *(const short8*)(Qhi + aoff + 32);
            short8 ql0 = *(const short8*)(Qlo + aoff);
            short8 ql1 = *(const short8*)(Qlo + aoff + 32);
#pragma unroll
            for (int nt = 0; nt < 4; ++nt) {
                const int n0 = w * 64 + nt * 16;
                const size_t boff = hb + (size_t)(n0 + mrow) * DHEAD + quad * 8;
                short8 kh0 = *(const short8*)(Khi + boff);
                short8 kh1 = *(const short8*)(Khi + boff + 32);
                short8 kl0 = *(const short8*)(Klo + boff);
                short8 kl1 = *(const short8*)(Klo + boff + 32);
                f32x4 d = (f32x4){0.f, 0.f, 0.f, 0.f};
                d = __builtin_amdgcn_mfma_f32_16x16x32_bf16(ql0, kh0, d, 0, 0, 0);
                d = __builtin_amdgcn_mfma_f32_16x16x32_bf16(qh0, kl0, d, 0, 0, 0);
                d = __builtin_amdgcn_mfma_f32_16x16x32_bf16(qh0, kh0, d, 0, 0, 0);
                d = __builtin_amdgcn_mfma_f32_16x16x32_bf16(ql1, kh1, d, 0, 0, 0);
                d = __builtin_amdgcn_mfma_f32_16x16x32_bf16(qh1, kl1, d, 0, 0, 0);
                d = __builtin_amdgcn_mfma_f32_16x16x32_bf16(qh1, kh1, d, 0, 0, 0);
                const int swcol = (n0 + mrow) ^ (quad << 4);   // 2-way banks (free)
#pragma unroll
                for (int reg = 0; reg < 4; ++reg)
                    S[(quad * 4 + reg) * 1024 + swcol] = d[reg] * 0.125f;
            }
        }
        __syncthreads();   // (a) S writes for head h complete

        // ---- z-load: wave w owns row w ----
        float z[16];
        {
            const int swz = ((w >> 2) & 3) << 4;   // inverse of write swizzle for row w
#pragma unroll
            for (int c = 0; c < 4; ++c)
                *(f32x4*)&z[c * 4] = *(const f32x4*)&S[w * 1024 + ((c * 256 + lane * 4) ^ swz)];
        }
        __syncthreads();   // (b) all waves consumed S; safe for next head's writes

        // ---- init: row sum, sumsq, max (4-way element chains) ----
        float sv, qv, mv;
        {
            float s0 = 0.f, s1 = 0.f, s2 = 0.f, s3 = 0.f;
            float p0 = 0.f, p1 = 0.f, p2 = 0.f, p3 = 0.f;
            float m0 = z[0], m1 = z[1], m2 = z[2], m3 = z[3];
#pragma unroll
            for (int j = 0; j < 16; j += 4) {
                s0 += z[j]; s1 += z[j + 1]; s2 += z[j + 2]; s3 += z[j + 3];
                p0 = fmaf(z[j],     z[j],     p0);
                p1 = fmaf(z[j + 1], z[j + 1], p1);
                p2 = fmaf(z[j + 2], z[j + 2], p2);
                p3 = fmaf(z[j + 3], z[j + 3], p3);
            }
#pragma unroll
            for (int j = 4; j < 16; j += 4) {
                m0 = fmaxf(m0, z[j]);     m1 = fmaxf(m1, z[j + 1]);
                m2 = fmaxf(m2, z[j + 2]); m3 = fmaxf(m3, z[j + 3]);
            }
            sv = (s0 + s1) + (s2 + s3);
            qv = (p0 + p1) + (p2 + p3);
            mv = fmaxf(fmaxf(m0, m1), fmaxf(m2, m3));
        }
        wred3(sv, qv, mv);

        // ---- warm start: Gaussian-tail analytic tau0 (validated in pass 1) ----
        const float t0s = fmaxf((sv - 1.0f) * (1.0f / 1024.0f), mv - 1.0f);
        float tau;
        {
            const float mu  = sv * (1.0f / 1024.0f);
            const float var = fmaxf(qv * (1.0f / 1024.0f) - mu * mu, 1e-12f);
            const float sg  = sqrtf(var);
            const float a   = 2.7196f + 0.33333f * __logf(sg);   // solves phi(a)-aQ(a)=1/(1024 sg)
            const float tg  = mu + (a - 0.25f) * sg;
            tau = fminf(fmaxf(tg, t0s), mv - 1e-3f);
        }

        // ballot-free masked pass: sum + count in float through one butterfly
#define SP_PASS(SC) do { \
        float a0 = 0.f, a1 = 0.f, a2 = 0.f, a3 = 0.f; \
        float n0 = 0.f, n1 = 0.f, n2 = 0.f, n3 = 0.f; \
        _Pragma("unroll") for (int j = 0; j < 16; j += 4) { \
            bool g0 = z[j]     > tau; \
            bool g1 = z[j + 1] > tau; \
            bool g2 = z[j + 2] > tau; \
            bool g3 = z[j + 3] > tau; \
            a0 += g0 ? z[j]     : 0.f;  n0 += g0 ? 1.f : 0.f; \
            a1 += g1 ? z[j + 1] : 0.f;  n1 += g1 ? 1.f : 0.f; \
            a2 += g2 ? z[j + 2] : 0.f;  n2 += g2 ? 1.f : 0.f; \
            a3 += g3 ? z[j + 3] : 0.f;  n3 += g3 ? 1.f : 0.f; \
        } \
        SC[0] = (a0 + a1) + (a2 + a3); \
        SC[1] = (n0 + n1) + (n2 + n3); \
        wsum2(SC); \
} while (0)

        float prev;
        // ---- pass 1: Michelot step with validity check ----
        {
            float sc[2];
            SP_PASS(sc);
            const float tn = (sc[0] - 1.0f) / sc[1];
            if (tn >= tau) { tau = tn; prev = sc[1]; }   // f(tau0)>=0: warm start valid
            else           { tau = t0s; prev = -1.f; }   // invalid/NaN: safe restart
        }
        // ---- Michelot loop (exact; per-wave uniform exit) ----
        for (int it = 0; it < 63; ++it) {
            float sc[2];
            SP_PASS(sc);
            if (sc[1] == prev) break;                    // support stable -> tau exact
            tau = (sc[0] - 1.0f) / sc[1];
            prev = sc[1];
        }
#undef SP_PASS

        // accumulate head-mean in registers (no LDS writeback)
#pragma unroll
        for (int j = 0; j < 16; ++j)
            macc[j] += fmaxf(z[j] - tau, 0.f);
    }

    float* ao = attn_out + ((size_t)b * LSEQ + q0) * LSEQ;
#pragma unroll
    for (int c = 0; c < 4; ++c) {
        f32x4 o;
#pragma unroll
        for (int j = 0; j < 4; ++j) o[j] = macc[c * 4 + j] * (1.0f / 12.0f);
        *(f32x4*)&ao[(size_t)w * LSEQ + c * 256 + lane * 4] = o;
    }
}

// ---------------------------------------------------------------------------
// out_mfma: out[b] = attn[b] @ v[b], 2-pass split-bf16, LDS-staged (R8 best).
// R15: dead A-lo staging removed (bit-identical, LDS 34->26 KB).
// ---------------------------------------------------------------------------
__global__ __launch_bounds__(256) void out_mfma(
    const float* __restrict__ attn, const float* __restrict__ v,
    float* __restrict__ out) {
    const int b = blockIdx.z;
    const float* Ab = attn + (size_t)b * LSEQ * LSEQ;
    const float* Vb = v    + (size_t)b * LSEQ * DMODEL;
    float* Cb       = out  + (size_t)b * LSEQ * DMODEL;

    __shared__ unsigned short Ah[128][32];
    __shared__ unsigned short Bh[128][36], Bl[128][36];   // pad 36: conflict-free 8B rd/wr

    const int t    = threadIdx.x;
    const int lane = t & 63;
    const int w    = t >> 6;
    const int wr   = w >> 1, wc = w & 1;
    const int mrow = lane & 15, quad = lane >> 4;
    const int m0   = blockIdx.y * 128;
    const int n0   = blockIdx.x * 128;

    const int srow = t >> 3;
    const int scol = (t & 7) * 4;
    const int bn   = t & 127;
    const int bk0  = (t >> 7) * 16;

    f32x4 acc[4][4];
#pragma unroll
    for (int i = 0; i < 4; ++i)
#pragma unroll
        for (int j = 0; j < 4; ++j) acc[i][j] = (f32x4){0.f, 0.f, 0.f, 0.f};

    for (int k0 = 0; k0 < LSEQ; k0 += 32) {
        float4 av[4];
#pragma unroll
        for (int i = 0; i < 4; ++i)
            av[i] = *(const float4*)&Ab[(size_t)(m0 + srow + i * 32) * LSEQ + k0 + scol];
        float bv[16];
#pragma unroll
        for (int i = 0; i < 16; ++i)
            bv[i] = Vb[(size_t)(k0 + bk0 + i) * DMODEL + n0 + bn];

        __syncthreads();
#pragma unroll
        for (int i = 0; i < 4; ++i) {
            ushort4 h4;
            h4.x = f2bf(av[i].x); h4.y = f2bf(av[i].y);
            h4.z = f2bf(av[i].z); h4.w = f2bf(av[i].w);
            *(ushort4*)&Ah[srow + i * 32][scol] = h4;
        }
#pragma unroll
        for (int g = 0; g < 4; ++g) {
            ushort4 h4, l4;
            split2(bv[g * 4 + 0], h4.x, l4.x); split2(bv[g * 4 + 1], h4.y, l4.y);
            split2(bv[g * 4 + 2], h4.z, l4.z); split2(bv[g * 4 + 3], h4.w, l4.w);
            *(ushort4*)&Bh[bn][bk0 + g * 4] = h4;
            *(ushort4*)&Bl[bn][bk0 + g * 4] = l4;
        }
        __syncthreads();

        short8 ah[4], bh[4], bl[4];
#pragma unroll
        for (int i = 0; i < 4; ++i)
            ah[i] = *(const short8*)&Ah[wr * 64 + i * 16 + mrow][quad * 8];
#pragma unroll
        for (int j = 0; j < 4; ++j) {
            const unsigned short* ph = &Bh[wc * 64 + j * 16 + mrow][quad * 8];
            const unsigned short* pl = &Bl[wc * 64 + j * 16 + mrow][quad * 8];
            uint2 h0 = *(const uint2*)ph;
            uint2 h1 = *(const uint2*)(ph + 4);
            uint2 l0 = *(const uint2*)pl;
            uint2 l1 = *(const uint2*)(pl + 4);
            union { uint u[4]; short8 s; } ch, cl;
            ch.u[0] = h0.x; ch.u[1] = h0.y; ch.u[2] = h1.x; ch.u[3] = h1.y;
            cl.u[0] = l0.x; cl.u[1] = l0.y; cl.u[2] = l1.x; cl.u[3] = l1.y;
            bh[j] = ch.s; bl[j] = cl.s;
        }
#pragma unroll
        for (int i = 0; i < 4; ++i)
#pragma unroll
            for (int j = 0; j < 4; ++j) {
                acc[i][j] = __builtin_amdgcn_mfma_f32_16x16x32_bf16(ah[i], bl[j], acc[i][j], 0, 0, 0);
                acc[i][j] = __builtin_amdgcn_mfma_f32_16x16x32_bf16(ah[i], bh[j], acc[i][j], 0, 0, 0);
            }
    }

#pragma unroll
    for (int i = 0; i < 4; ++i)
#pragma unroll
        for (int j = 0; j < 4; ++j)
#pragma unroll
            for (int reg = 0; reg < 4; ++reg) {
                const int mg = m0 + wr * 64 + i * 16 + quad * 4 + reg;
                const int ng = n0 + wc * 64 + j * 16 + mrow;
                Cb[(size_t)mg * DMODEL + ng] = acc[i][j][reg];
            }
}

extern "C" void kernel_launch(void* const* d_in, const int* in_sizes, int n_in,
                              void* d_out, int out_size, void* d_ws, size_t ws_size,
                              hipStream_t stream) {
    const float* q  = (const float*)d_in[0];
    const float* k  = (const float*)d_in[1];
    const float* v  = (const float*)d_in[2];
    const float* Wq = (const float*)d_in[3];
    const float* bq = (const float*)d_in[4];
    const float* Wk = (const float*)d_in[5];
    const float* bk = (const float*)d_in[6];

    float* out  = (float*)d_out;                 // [8,1024,768]
    float* attn = out + OUT_ELEMS;               // [8,1024,1024]
    unsigned short* ws = (unsigned short*)d_ws;  // Qhi|Qlo|Khi|Klo bf16 planes (50 MB)

    hipLaunchKernelGGL(proj_mfma, dim3(6, 64, 2), dim3(256), 0, stream,
                       q, k, Wq, bq, Wk, bk, ws);
    hipLaunchKernelGGL(attn_kernel, dim3(512), dim3(1024), 0, stream,
                       ws, attn);
    hipLaunchKernelGGL(out_mfma, dim3(6, 8, 8), dim3(256), 0, stream,
                       attn, v, out);
}